// Round 7
// baseline (388.755 us; speedup 1.0000x reference)
//
#include <hip/hip_runtime.h>

// GraphSAGE 2-layer, fp32 in/out, MI355X.
//   CSR build -> mean1 = agg(x)/cnt
//   fused: H = relu([mean1|x]@[W1l|W1r]^T + b1) -> LDS hi/lo -> Y2Z = H@[W2l;W2r]^T (+b2 on Z)
//   out = agg(Y2)/cnt + Z
// Split-bf16: v = hi + lo; A@B ~= Ahi@Bhi + Ahi@Blo + Alo@Bhi (fp32 acc, ~2^-16 rel err)
// R6: fragments DIRECT global->register (weights pre-split in B-frag layout; A via float4+cvt).
//     LDS only for H (the one true cross-wave k-redistribution). ONE barrier per block
//     (R6 profile: fused 154us, MfmaUtil 15%, FETCH 54MB -> barrier/staging-bound, not traffic).

#define IN_CH  128
#define HID_CH 256
#define OUT_CH 64

typedef __bf16 bf16x8 __attribute__((ext_vector_type(8)));
typedef float  f32x4  __attribute__((ext_vector_type(4)));

// ---------------- CSR build ----------------

__global__ void hist_kernel(const int* __restrict__ dst, int* __restrict__ deg, int E) {
    for (int e = blockIdx.x * blockDim.x + threadIdx.x; e < E; e += gridDim.x * blockDim.x)
        atomicAdd(&deg[dst[e]], 1);
}

__global__ void scan_block(const int* __restrict__ deg, int* __restrict__ offs,
                           int* __restrict__ bsum, int n) {
    __shared__ int s[512];
    int i = blockIdx.x * 512 + threadIdx.x;
    int v = (i < n) ? deg[i] : 0;
    s[threadIdx.x] = v;
    __syncthreads();
    #pragma unroll
    for (int d = 1; d < 512; d <<= 1) {
        int t = (threadIdx.x >= d) ? s[threadIdx.x - d] : 0;
        __syncthreads();
        s[threadIdx.x] += t;
        __syncthreads();
    }
    if (i < n) offs[i] = s[threadIdx.x] - v;
    if (threadIdx.x == 511) bsum[blockIdx.x] = s[511];
}

__global__ void scan_sums(int* __restrict__ bsum, int nb) {
    __shared__ int s[256];
    int v = (threadIdx.x < nb) ? bsum[threadIdx.x] : 0;
    s[threadIdx.x] = v;
    __syncthreads();
    #pragma unroll
    for (int d = 1; d < 256; d <<= 1) {
        int t = (threadIdx.x >= d) ? s[threadIdx.x - d] : 0;
        __syncthreads();
        s[threadIdx.x] += t;
        __syncthreads();
    }
    if (threadIdx.x < nb) bsum[threadIdx.x] = s[threadIdx.x] - v;
}

__global__ void scan_add(int* __restrict__ offs, const int* __restrict__ bsum, int n, int E) {
    int i = blockIdx.x * blockDim.x + threadIdx.x;
    if (i < n) offs[i] += bsum[i >> 9];
    if (i == 0) offs[n] = E;
}

__global__ void fill_csr(const int* __restrict__ src, const int* __restrict__ dst,
                         const int* __restrict__ offs, int* __restrict__ cur,
                         int* __restrict__ srcs, int E) {
    for (int e = blockIdx.x * blockDim.x + threadIdx.x; e < E; e += gridDim.x * blockDim.x) {
        int d = dst[e];
        int p = atomicAdd(&cur[d], 1);
        srcs[offs[d] + p] = src[e];
    }
}

// ---------------- weight split (fp32 -> bf16 hi/lo), once per launch ----------------

__global__ void convert_weights(const float* __restrict__ W1l, const float* __restrict__ W1r,
                                const float* __restrict__ W2l, const float* __restrict__ W2r,
                                const float* __restrict__ b2,
                                __bf16* __restrict__ W1h, __bf16* __restrict__ W1lo,
                                __bf16* __restrict__ W2h, __bf16* __restrict__ W2lo,
                                float* __restrict__ bias2) {
    int i = blockIdx.x * 256 + threadIdx.x;
    if (i < 256 * 256) {                 // W1cat [256][256]: k<128 from W1l, else W1r
        int n = i >> 8, k = i & 255;
        float v = (k < 128) ? W1l[n * 128 + k] : W1r[n * 128 + (k - 128)];
        __bf16 h = (__bf16)v;
        W1h[i] = h; W1lo[i] = (__bf16)(v - (float)h);
    }
    if (i < 128 * 256) {                 // W2cat [128][256]: n<64 from W2l (Y2), else W2r (Z)
        int n = i >> 8, k = i & 255;
        float v = (n < 64) ? W2l[n * 256 + k] : W2r[(n - 64) * 256 + k];
        __bf16 h = (__bf16)v;
        W2h[i] = h; W2lo[i] = (__bf16)(v - (float)h);
    }
    if (i < 128) bias2[i] = (i < 64) ? 0.f : b2[i - 64];
}

// ---------------- aggregation (multi-node waves, 4x unrolled gathers) ----------------

// 2 nodes per wave: 32 lanes x float4 = 512B = one 128-ch fp32 row.
__global__ __launch_bounds__(256) void agg_mean128(
    const float* __restrict__ X, const int* __restrict__ offs,
    const int* __restrict__ srcs, float* __restrict__ outm, int N) {
    int wv = (blockIdx.x * 256 + threadIdx.x) >> 6;
    int lane = threadIdx.x & 63;
    int grp = lane >> 5, l = lane & 31;
    int node = wv * 2 + grp;
    if (node >= N) return;
    int s0 = offs[node], s1 = offs[node + 1];
    float ax = 0.f, ay = 0.f, az = 0.f, aw = 0.f;
    int k = s0;
    for (; k + 4 <= s1; k += 4) {
        int i0 = srcs[k], i1 = srcs[k + 1], i2 = srcs[k + 2], i3 = srcs[k + 3];
        float4 a = *(const float4*)(X + (size_t)i0 * 128 + l * 4);
        float4 b = *(const float4*)(X + (size_t)i1 * 128 + l * 4);
        float4 c = *(const float4*)(X + (size_t)i2 * 128 + l * 4);
        float4 d = *(const float4*)(X + (size_t)i3 * 128 + l * 4);
        ax += (a.x + b.x) + (c.x + d.x);
        ay += (a.y + b.y) + (c.y + d.y);
        az += (a.z + b.z) + (c.z + d.z);
        aw += (a.w + b.w) + (c.w + d.w);
    }
    for (; k < s1; ++k) {
        int s = srcs[k];
        float4 a = *(const float4*)(X + (size_t)s * 128 + l * 4);
        ax += a.x; ay += a.y; az += a.z; aw += a.w;
    }
    int c = s1 - s0;
    float sc = 1.0f / (float)(c > 1 ? c : 1);
    float4 r; r.x = ax * sc; r.y = ay * sc; r.z = az * sc; r.w = aw * sc;
    *(float4*)(outm + (size_t)node * 128 + l * 4) = r;
}

// 4 nodes per wave: 16 lanes x float4 = 256B = one 64-ch Y2 row.
__global__ __launch_bounds__(256) void agg_add_out(
    const float* __restrict__ Y2Z, const int* __restrict__ offs,
    const int* __restrict__ srcs, float* __restrict__ out, int N) {
    int wv = (blockIdx.x * 256 + threadIdx.x) >> 6;
    int lane = threadIdx.x & 63;
    int grp = lane >> 4, l = lane & 15;
    int node = wv * 4 + grp;
    if (node >= N) return;
    int s0 = offs[node], s1 = offs[node + 1];
    float4 z = *(const float4*)(Y2Z + (size_t)node * 128 + 64 + l * 4);
    float ax = 0.f, ay = 0.f, az = 0.f, aw = 0.f;
    int k = s0;
    for (; k + 4 <= s1; k += 4) {
        int i0 = srcs[k], i1 = srcs[k + 1], i2 = srcs[k + 2], i3 = srcs[k + 3];
        float4 a = *(const float4*)(Y2Z + (size_t)i0 * 128 + l * 4);
        float4 b = *(const float4*)(Y2Z + (size_t)i1 * 128 + l * 4);
        float4 c = *(const float4*)(Y2Z + (size_t)i2 * 128 + l * 4);
        float4 d = *(const float4*)(Y2Z + (size_t)i3 * 128 + l * 4);
        ax += (a.x + b.x) + (c.x + d.x);
        ay += (a.y + b.y) + (c.y + d.y);
        az += (a.z + b.z) + (c.z + d.z);
        aw += (a.w + b.w) + (c.w + d.w);
    }
    for (; k < s1; ++k) {
        int s = srcs[k];
        float4 a = *(const float4*)(Y2Z + (size_t)s * 128 + l * 4);
        ax += a.x; ay += a.y; az += a.z; aw += a.w;
    }
    int c = s1 - s0;
    float sc = 1.0f / (float)(c > 1 ? c : 1);
    float4 r;
    r.x = ax * sc + z.x; r.y = ay * sc + z.y;
    r.z = az * sc + z.z; r.w = aw * sc + z.w;
    *(float4*)(out + (size_t)node * 64 + l * 4) = r;
}

// ---------------- fused L1+L2 GEMM, direct-fragment edition ----------------
// Per block: 64 nodes, 256 threads = 4 waves. ONE __syncthreads total.
// Phase A (no LDS, no barrier): acc[64x256] = split-bf16([mean1|x]@W1cat^T).
//   A-frags: per-lane 2x float4 from global + cvt to hi/lo. W1-frags: per-lane
//   16B bf16x8 loads (pre-split global IS the B-fragment layout: W[rb][k0+lg*8]).
//   Wave w -> output cols w*64..w*64+63.
// Phase B: H = relu(acc+b1) -> hi/lo bf16 LDS [64][256], swizzle ^((row&7)<<4). 1 barrier.
// Phase C (no barrier): Y2Z[64][128] = split-bf16(H@W2cat^T)+bias2; H-frags ds_read_b128
//   (conflict-free: 8 dwords/bank = b128 minimum), W2-frags direct global. Wave w -> cols w*32..
// LDS = 64KB (H only) -> 2 blocks/CU; launch_bounds(256,2) caps VGPR at 256.

__global__ __launch_bounds__(256, 2) void fused_l1l2(
    const float* __restrict__ mean1, const float* __restrict__ x,
    const __bf16* __restrict__ W1h, const __bf16* __restrict__ W1lo,
    const float* __restrict__ b1,
    const __bf16* __restrict__ W2h, const __bf16* __restrict__ W2lo,
    const float* __restrict__ bias2,
    float* __restrict__ Y2Z, int N) {
    __shared__ __align__(16) __bf16 Hh[64 * 256];   // 32 KB
    __shared__ __align__(16) __bf16 Hl[64 * 256];   // 32 KB

    const int tid = threadIdx.x;
    const int lane = tid & 63;
    const int w = tid >> 6;                         // wave 0..3
    const int l15 = lane & 15, lg = lane >> 4;
    const long row0 = (long)blockIdx.x * 64;

    // ---- phase A: acc = [mean1|x] @ W1cat^T (3-product split), zero barriers ----
    f32x4 acc[4][4] = {};
    #pragma unroll
    for (int ks = 0; ks < 8; ++ks) {
        const float* __restrict__ Asrc = (ks < 4) ? mean1 : x;
        const int kk0 = ((ks < 4) ? ks * 32 : (ks - 4) * 32) + lg * 8;   // col in source
        const int k0 = ks * 32;                                          // col in W1cat

        bf16x8 ah[4], al[4];
        #pragma unroll
        for (int m = 0; m < 4; ++m) {
            long gr = row0 + m * 16 + l15;
            float4 v0 = make_float4(0.f, 0.f, 0.f, 0.f);
            float4 v1 = make_float4(0.f, 0.f, 0.f, 0.f);
            if (gr < N) {
                v0 = *(const float4*)(Asrc + gr * 128 + kk0);
                v1 = *(const float4*)(Asrc + gr * 128 + kk0 + 4);
            }
            float f0 = v0.x, f1 = v0.y, f2 = v0.z, f3 = v0.w;
            float f4 = v1.x, f5 = v1.y, f6 = v1.z, f7 = v1.w;
            bf16x8 h, l;
            h[0] = (__bf16)f0; h[1] = (__bf16)f1; h[2] = (__bf16)f2; h[3] = (__bf16)f3;
            h[4] = (__bf16)f4; h[5] = (__bf16)f5; h[6] = (__bf16)f6; h[7] = (__bf16)f7;
            l[0] = (__bf16)(f0 - (float)h[0]); l[1] = (__bf16)(f1 - (float)h[1]);
            l[2] = (__bf16)(f2 - (float)h[2]); l[3] = (__bf16)(f3 - (float)h[3]);
            l[4] = (__bf16)(f4 - (float)h[4]); l[5] = (__bf16)(f5 - (float)h[5]);
            l[6] = (__bf16)(f6 - (float)h[6]); l[7] = (__bf16)(f7 - (float)h[7]);
            ah[m] = h; al[m] = l;
        }
        bf16x8 bh[4], bl[4];
        #pragma unroll
        for (int n = 0; n < 4; ++n) {
            int rb = w * 64 + n * 16 + l15;
            long g = (long)rb * 256 + k0 + lg * 8;
            bh[n] = *(const bf16x8*)(W1h + g);
            bl[n] = *(const bf16x8*)(W1lo + g);
        }
        #pragma unroll
        for (int m = 0; m < 4; ++m)
            #pragma unroll
            for (int n = 0; n < 4; ++n) {
                acc[m][n] = __builtin_amdgcn_mfma_f32_16x16x32_bf16(ah[m], bh[n], acc[m][n], 0, 0, 0);
                acc[m][n] = __builtin_amdgcn_mfma_f32_16x16x32_bf16(ah[m], bl[n], acc[m][n], 0, 0, 0);
                acc[m][n] = __builtin_amdgcn_mfma_f32_16x16x32_bf16(al[m], bh[n], acc[m][n], 0, 0, 0);
            }
    }

    // ---- phase B: H = relu(acc + b1) -> hi/lo LDS ----
    #pragma unroll
    for (int n = 0; n < 4; ++n) {
        int col = w * 64 + n * 16 + l15;
        float bv = b1[col];
        #pragma unroll
        for (int m = 0; m < 4; ++m) {
            #pragma unroll
            for (int rr = 0; rr < 4; ++rr) {
                int row = m * 16 + lg * 4 + rr;
                float v = fmaxf(acc[m][n][rr] + bv, 0.f);
                __bf16 hv = (__bf16)v;
                __bf16 lv = (__bf16)(v - (float)hv);
                int off = (row * 512 + col * 2) ^ ((row & 7) << 4);
                *(__bf16*)((char*)Hh + off) = hv;
                *(__bf16*)((char*)Hl + off) = lv;
            }
        }
    }
    __syncthreads();   // the only barrier

    // ---- phase C: Y2Z = H @ W2cat^T + bias2, zero barriers ----
    f32x4 acc2[4][2] = {};
    #pragma unroll
    for (int ks = 0; ks < 8; ++ks) {
        const int k0 = ks * 32;
        bf16x8 a2h[4], a2l[4];
        #pragma unroll
        for (int m = 0; m < 4; ++m) {
            int row = m * 16 + l15;
            int off = (row * 512 + k0 * 2 + lg * 16) ^ ((row & 7) << 4);
            a2h[m] = *(const bf16x8*)((char*)Hh + off);
            a2l[m] = *(const bf16x8*)((char*)Hl + off);
        }
        bf16x8 c2h[2], c2l[2];
        #pragma unroll
        for (int n = 0; n < 2; ++n) {
            int rb = w * 32 + n * 16 + l15;
            long g = (long)rb * 256 + k0 + lg * 8;
            c2h[n] = *(const bf16x8*)(W2h + g);
            c2l[n] = *(const bf16x8*)(W2lo + g);
        }
        #pragma unroll
        for (int m = 0; m < 4; ++m)
            #pragma unroll
            for (int n = 0; n < 2; ++n) {
                acc2[m][n] = __builtin_amdgcn_mfma_f32_16x16x32_bf16(a2h[m], c2h[n], acc2[m][n], 0, 0, 0);
                acc2[m][n] = __builtin_amdgcn_mfma_f32_16x16x32_bf16(a2h[m], c2l[n], acc2[m][n], 0, 0, 0);
                acc2[m][n] = __builtin_amdgcn_mfma_f32_16x16x32_bf16(a2l[m], c2h[n], acc2[m][n], 0, 0, 0);
            }
    }

    // ---- epilogue: Y2Z (+bias2: 0 on Y2 half, b2 on Z half) ----
    #pragma unroll
    for (int n = 0; n < 2; ++n) {
        int gc = w * 32 + n * 16 + l15;
        float bv = bias2[gc];
        #pragma unroll
        for (int m = 0; m < 4; ++m) {
            #pragma unroll
            for (int rr = 0; rr < 4; ++rr) {
                long gr = row0 + m * 16 + lg * 4 + rr;
                if (gr < N) Y2Z[gr * 128 + gc] = acc2[m][n][rr] + bv;
            }
        }
    }
}

// ---------------- launch ----------------

extern "C" void kernel_launch(void* const* d_in, const int* in_sizes, int n_in,
                              void* d_out, int out_size, void* d_ws, size_t ws_size,
                              hipStream_t stream) {
    const float* x   = (const float*)d_in[0];
    const int*   ei  = (const int*)d_in[1];
    const float* W1l = (const float*)d_in[2];
    const float* b1  = (const float*)d_in[3];
    const float* W1r = (const float*)d_in[4];
    const float* W2l = (const float*)d_in[5];
    const float* b2  = (const float*)d_in[6];
    const float* W2r = (const float*)d_in[7];
    float* out = (float*)d_out;

    const int N = in_sizes[0] / IN_CH;      // 100000
    const int E = in_sizes[1] / 2;          // 640000
    const int* src = ei;
    const int* dst = ei + E;

    // ws carve: buf1=mean1[N*128] | buf2=Y2Z[N*128] | CSR ints | bf16 weight splits | bias2
    float* buf1 = (float*)d_ws;
    float* buf2 = buf1 + (size_t)N * 128;
    int* deg  = (int*)(buf2 + (size_t)N * 128);
    int* offs = deg + N;
    int* cur  = offs + (N + 8);
    int* bsum = cur + N;
    int* srcs = bsum + 512;
    uintptr_t pp = (uintptr_t)(srcs + E);
    pp = (pp + 15) & ~(uintptr_t)15;
    __bf16* W1h  = (__bf16*)pp;             // [256][256]
    __bf16* W1lo = W1h + 256 * 256;
    __bf16* W2h  = W1lo + 256 * 256;        // [128][256]
    __bf16* W2lo = W2h + 128 * 256;
    float* bias2 = (float*)(W2lo + 128 * 256);

    hipMemsetAsync(deg, 0, sizeof(int) * N, stream);
    hipMemsetAsync(cur, 0, sizeof(int) * N, stream);

    convert_weights<<<256, 256, 0, stream>>>(W1l, W1r, W2l, W2r, b2,
                                             W1h, W1lo, W2h, W2lo, bias2);

    hist_kernel<<<1024, 256, 0, stream>>>(dst, deg, E);
    int nb = (N + 511) / 512;
    scan_block<<<nb, 512, 0, stream>>>(deg, offs, bsum, N);
    scan_sums<<<1, 256, 0, stream>>>(bsum, nb);
    scan_add<<<(N + 255) / 256, 256, 0, stream>>>(offs, bsum, N, E);
    fill_csr<<<1024, 256, 0, stream>>>(src, dst, offs, cur, srcs, E);

    agg_mean128<<<((N + 1) / 2 * 64 + 255) / 256, 256, 0, stream>>>(x, offs, srcs, buf1, N);

    fused_l1l2<<<(N + 63) / 64, 256, 0, stream>>>(buf1, x, W1h, W1lo, b1,
                                                  W2h, W2lo, bias2, buf2, N);

    agg_add_out<<<((N + 3) / 4 * 64 + 255) / 256, 256, 0, stream>>>(buf2, offs, srcs, out, N);
}